// Round 2
// baseline (49.761 us; speedup 1.0000x reference)
//
#include <hip/hip_runtime.h>

// MultiVectorFieldModel: per-point routed tiny MLP (17 -> 6 -> 16), 65 models.
// Weights per model flattened to 220 floats:
//   [0..101]   W1  (i*6+j)
//   [102..107] b1
//   [108..203] W2  (j*16+d)
//   [204..219] b2
// LDS layout: wlds[k][model] (model-minor, SCALAR floats). Gather address for
// lane with model `mid` at weight k is (k*65 + mid)*4B; 65 % 32 == 1, so
// bank = (mid + k) % 32 -> 64 random lanes spread over all 32 banks
// (2 lanes/bank average = conflict-free). k folds into the ds_read_b32
// offset: immediate (max 219*260 = 56940 < 65536).

#define NMODELS 65
#define WPM 220           // weights per model
#define BLOCK 1024

__global__ __launch_bounds__(BLOCK) void mvf_kernel(
    const float* __restrict__ x,
    const float* __restrict__ W1,
    const float* __restrict__ b1,
    const float* __restrict__ W2,
    const float* __restrict__ b2,
    float* __restrict__ out,
    int npts)
{
    __shared__ float wlds[WPM][NMODELS];   // 220*65*4 = 57200 B
    const int tid = threadIdx.x;

    // ---- stage weights into LDS ----
    // consecutive threads: same m, consecutive k -> LDS bank stride 1 (no
    // conflicts), global reads coalesced within each array.
    for (int e = tid; e < NMODELS * WPM; e += BLOCK) {
        const int m = e / WPM, k = e % WPM;
        float v;
        if (k < 102)      v = W1[m * 102 + k];
        else if (k < 108) v = b1[m * 6 + (k - 102)];
        else if (k < 204) v = W2[m * 96 + (k - 108)];
        else              v = b2[m * 16 + (k - 204)];
        wlds[k][m] = v;
    }
    __syncthreads();

    const int p = blockIdx.x * BLOCK + tid;
    if (p >= npts) return;

    // ---- load x row: 18 floats, rows are 72B (8B-aligned) ----
    float xf[18];
    const float2* xr = (const float2*)(x + (long)p * 18);
    #pragma unroll
    for (int i = 0; i < 9; ++i) {
        float2 v = xr[i];
        xf[2 * i] = v.x;
        xf[2 * i + 1] = v.y;
    }
    const float t = xf[17];
    const int c = (int)xf[16];
    int bucket = (int)floorf(t * 8.0f);
    bucket = bucket < 0 ? 0 : (bucket > 7 ? 7 : bucket);
    const int mid = (c == 0) ? 0 : 1 + (c - 1) * 8 + bucket;

    // xin = [data[0..15], t]
    xf[16] = t;

    // ---- h = relu(xin @ W1 + b1) ----
    float h[6];
    #pragma unroll
    for (int j = 0; j < 6; ++j) h[j] = wlds[102 + j][mid];
    #pragma unroll
    for (int i = 0; i < 17; ++i) {
        const float xi = xf[i];
        #pragma unroll
        for (int j = 0; j < 6; ++j)
            h[j] = fmaf(xi, wlds[i * 6 + j][mid], h[j]);
    }
    #pragma unroll
    for (int j = 0; j < 6; ++j) h[j] = h[j] > 0.0f ? h[j] : 0.0f;

    // ---- out = h @ W2 + b2 ----
    float o[16];
    #pragma unroll
    for (int d = 0; d < 16; ++d) o[d] = wlds[204 + d][mid];
    #pragma unroll
    for (int j = 0; j < 6; ++j) {
        const float hj = h[j];
        #pragma unroll
        for (int d = 0; d < 16; ++d)
            o[d] = fmaf(hj, wlds[108 + j * 16 + d][mid], o[d]);
    }

    // ---- store: 16 floats = 4 x float4, 64B rows (aligned) ----
    float4* orow = (float4*)(out + (long)p * 16);
    #pragma unroll
    for (int q = 0; q < 4; ++q) {
        orow[q] = make_float4(o[4 * q], o[4 * q + 1], o[4 * q + 2], o[4 * q + 3]);
    }
}

extern "C" void kernel_launch(void* const* d_in, const int* in_sizes, int n_in,
                              void* d_out, int out_size, void* d_ws, size_t ws_size,
                              hipStream_t stream) {
    const float* x  = (const float*)d_in[0];
    const float* W1 = (const float*)d_in[1];
    const float* b1 = (const float*)d_in[2];
    const float* W2 = (const float*)d_in[3];
    const float* b2 = (const float*)d_in[4];
    float* out = (float*)d_out;

    const int npts = in_sizes[0] / 18;
    const int grid = (npts + BLOCK - 1) / BLOCK;
    mvf_kernel<<<grid, BLOCK, 0, stream>>>(x, W1, b1, W2, b2, out, npts);
}

// Round 3
// 44.868 us; speedup vs baseline: 1.1091x; 1.1091x over previous
//
#include <hip/hip_runtime.h>

// MultiVectorFieldModel: per-point routed tiny MLP (17 -> 6 -> 16), 65 models.
// Weights per model flattened to 220 floats:
//   [0..101]   W1  (flat i*6+j)
//   [102..107] b1
//   [108..203] W2  (flat j*16+d)
//   [204..219] b2
// LDS layout: float4 chunks, model-minor: wlds[k4][model], k4 = 0..54.
// Gather = ds_read_b128 at base mid*16, k4 folds into offset: immediate
// (max 54*1040 = 56160 < 65536). A wave64 b128 read takes >=8 cycles
// (1KB / 128B-per-clk); the 65-model address spread gives ~8-9 distinct
// addresses per 4-bank group, so conflict serialization hides under the
// minimum transfer time. 55 LDS instructions/point (vs 220 scalar).

#define NMODELS 65
#define WPM 220
#define NCHUNK 55
#define BLOCK 1024

__global__ __launch_bounds__(BLOCK, 8) void mvf_kernel(
    const float* __restrict__ x,
    const float* __restrict__ W1,
    const float* __restrict__ b1,
    const float* __restrict__ W2,
    const float* __restrict__ b2,
    float* __restrict__ out,
    int npts)
{
    __shared__ float4 wlds[NCHUNK][NMODELS];   // 55*65*16 = 57200 B
    const int tid = threadIdx.x;

    // ---- stage weights into LDS (scalar repack into float4 chunks) ----
    float* wf = (float*)wlds;
    for (int e = tid; e < NMODELS * WPM; e += BLOCK) {
        const int m = e / WPM, k = e % WPM;
        float v;
        if (k < 102)      v = W1[m * 102 + k];
        else if (k < 108) v = b1[m * 6 + (k - 102)];
        else if (k < 204) v = W2[m * 96 + (k - 108)];
        else              v = b2[m * 16 + (k - 204)];
        wf[(k >> 2) * (NMODELS * 4) + m * 4 + (k & 3)] = v;
    }
    __syncthreads();

    const int p = blockIdx.x * BLOCK + tid;
    if (p >= npts) return;

    // ---- load x row: 18 floats, rows are 72B (8B-aligned) ----
    float xf[18];
    const float2* xr = (const float2*)(x + (long)p * 18);
    #pragma unroll
    for (int i = 0; i < 9; ++i) {
        float2 v = xr[i];
        xf[2 * i]     = v.x;
        xf[2 * i + 1] = v.y;
    }
    const float t = xf[17];
    const int c = (int)xf[16];
    int bucket = (int)floorf(t * 8.0f);
    bucket = bucket < 0 ? 0 : (bucket > 7 ? 7 : bucket);
    const int mid = (c == 0) ? 0 : 1 + (c - 1) * 8 + bucket;

    // ---- h = relu(xin @ W1 + b1), xin = [data[0..15], t] ----
    float h[6];
    {
        // chunk 24 = W1 flat 96..99 (row16 j0..3), chunk 25 = {W1[100],W1[101],b1[0],b1[1]},
        // chunk 26 = b1[2..5]
        float4 c24 = wlds[24][mid];
        float4 c25 = wlds[25][mid];
        float4 c26 = wlds[26][mid];
        h[0] = fmaf(t, c24.x, c25.z);
        h[1] = fmaf(t, c24.y, c25.w);
        h[2] = fmaf(t, c24.z, c26.x);
        h[3] = fmaf(t, c24.w, c26.y);
        h[4] = fmaf(t, c25.x, c26.z);
        h[5] = fmaf(t, c25.y, c26.w);
    }
    #pragma unroll
    for (int r = 0; r < 8; ++r) {
        // rows 2r, 2r+1 = flat floats 12r..12r+11 = chunks 3r, 3r+1, 3r+2
        float4 a = wlds[3 * r + 0][mid];
        float4 b = wlds[3 * r + 1][mid];
        float4 d = wlds[3 * r + 2][mid];
        const float x0 = xf[2 * r], x1 = xf[2 * r + 1];
        h[0] = fmaf(x0, a.x, h[0]);
        h[1] = fmaf(x0, a.y, h[1]);
        h[2] = fmaf(x0, a.z, h[2]);
        h[3] = fmaf(x0, a.w, h[3]);
        h[4] = fmaf(x0, b.x, h[4]);
        h[5] = fmaf(x0, b.y, h[5]);
        h[0] = fmaf(x1, b.z, h[0]);
        h[1] = fmaf(x1, b.w, h[1]);
        h[2] = fmaf(x1, d.x, h[2]);
        h[3] = fmaf(x1, d.y, h[3]);
        h[4] = fmaf(x1, d.z, h[4]);
        h[5] = fmaf(x1, d.w, h[5]);
    }
    #pragma unroll
    for (int j = 0; j < 6; ++j) h[j] = h[j] > 0.0f ? h[j] : 0.0f;

    // ---- out = h @ W2 + b2 ----
    // b2 = chunks 51..54; W2 row j = chunks 27+4j .. 27+4j+3 (d-major)
    float o[16];
    #pragma unroll
    for (int q = 0; q < 4; ++q) {
        float4 v = wlds[51 + q][mid];
        o[4 * q + 0] = v.x;
        o[4 * q + 1] = v.y;
        o[4 * q + 2] = v.z;
        o[4 * q + 3] = v.w;
    }
    #pragma unroll
    for (int j = 0; j < 6; ++j) {
        const float hj = h[j];
        #pragma unroll
        for (int q = 0; q < 4; ++q) {
            float4 v = wlds[27 + 4 * j + q][mid];
            o[4 * q + 0] = fmaf(hj, v.x, o[4 * q + 0]);
            o[4 * q + 1] = fmaf(hj, v.y, o[4 * q + 1]);
            o[4 * q + 2] = fmaf(hj, v.z, o[4 * q + 2]);
            o[4 * q + 3] = fmaf(hj, v.w, o[4 * q + 3]);
        }
    }

    // ---- store: 16 floats = 4 x float4, 64B rows (aligned) ----
    float4* orow = (float4*)(out + (long)p * 16);
    #pragma unroll
    for (int q = 0; q < 4; ++q) {
        orow[q] = make_float4(o[4 * q], o[4 * q + 1], o[4 * q + 2], o[4 * q + 3]);
    }
}

extern "C" void kernel_launch(void* const* d_in, const int* in_sizes, int n_in,
                              void* d_out, int out_size, void* d_ws, size_t ws_size,
                              hipStream_t stream) {
    const float* x  = (const float*)d_in[0];
    const float* W1 = (const float*)d_in[1];
    const float* b1 = (const float*)d_in[2];
    const float* W2 = (const float*)d_in[3];
    const float* b2 = (const float*)d_in[4];
    float* out = (float*)d_out;

    const int npts = in_sizes[0] / 18;
    const int grid = (npts + BLOCK - 1) / BLOCK;
    mvf_kernel<<<grid, BLOCK, 0, stream>>>(x, W1, b1, W2, b2, out, npts);
}